// Round 2
// baseline (1678.351 us; speedup 1.0000x reference)
//
#include <hip/hip_runtime.h>

// ---------------------------------------------------------------------------
// GraphSAGE 2-layer (mean aggr) + linear classifier, fp32, N=100K, D=64, E=16N
// R6: atomic-free radix-bucket build replaces atomic-scatter CSR.
//  R5 counters: scatter WRITE_SIZE=105.8MB for a 6.4MB col array (16x write
//  amplification from 4B scattered stores across 100K frontiers) at 830 GB/s
//  => writeback-bound. Fix: bucket edges by dst>>7 (782 buckets x 128 nodes)
//  via per-block LDS histogram + global scan + LDS-cursor placement (zero
//  global atomics; 8192 edges/block => ~42B per (block,bucket) chunk, dense
//  concurrent frontiers => full line fill). Aggregate becomes one block per
//  bucket with a 32KB LDS fp32 accumulator fed by ds_add_f32; deg is counted
//  in LDS, deleting the zero+hist kernels (1.6M global atomics) entirely.
// Linear kernels unchanged (wave-uniform weight s_loads).
// ---------------------------------------------------------------------------

#define SCAN_BS 1024
#define BUCKET_BITS 7
#define BUCKET_NODES 128        // nodes per bucket
#define NBUCK_MAX 1024          // LDS histogram capacity (B = 782 for N=100K)
#define EPB 8192                // edges per block in hist/place passes

// --- K1: per-block bucket histogram -> counts[k * NB + b] (bucket-major) ---
__global__ void __launch_bounds__(256) bucket_hist_kernel(const int* __restrict__ dst,
                                                          int* __restrict__ counts,
                                                          int ne, int B, int NB) {
  __shared__ int hist[NBUCK_MAX];
  for (int k = threadIdx.x; k < B; k += 256) hist[k] = 0;
  __syncthreads();
  int base = blockIdx.x * EPB;
#pragma unroll 4
  for (int i = 0; i < EPB / 256; ++i) {
    int e = base + i * 256 + threadIdx.x;
    if (e < ne) atomicAdd(&hist[dst[e] >> BUCKET_BITS], 1);
  }
  __syncthreads();
  for (int k = threadIdx.x; k < B; k += 256) counts[k * NB + blockIdx.x] = hist[k];
}

// --- 2-level scan (in-place exclusive over counts) ---
__device__ __forceinline__ int block_scan_inclusive_1024(int v, int* wsums) {
  int lane = threadIdx.x & 63;
  int wid = threadIdx.x >> 6;
  int s = v;
#pragma unroll
  for (int off = 1; off < 64; off <<= 1) {
    int t = __shfl_up(s, off);
    if (lane >= off) s += t;
  }
  if (lane == 63) wsums[wid] = s;
  __syncthreads();
  if (wid == 0) {
    int ws = (lane < 16) ? wsums[lane] : 0;
#pragma unroll
    for (int off = 1; off < 16; off <<= 1) {
      int t = __shfl_up(ws, off);
      if (lane >= off) ws += t;
    }
    if (lane < 16) wsums[lane] = ws;
  }
  __syncthreads();
  if (wid > 0) s += wsums[wid - 1];
  return s;
}

__global__ void __launch_bounds__(SCAN_BS) scan_a_inplace_kernel(int* __restrict__ data,
                                                                 int* __restrict__ bsums,
                                                                 int S) {
  __shared__ int wsums[16];
  int i = blockIdx.x * SCAN_BS + threadIdx.x;
  int v = (i < S) ? data[i] : 0;
  int inc = block_scan_inclusive_1024(v, wsums);
  if (i < S) data[i] = inc - v;  // exclusive, block-local
  if (threadIdx.x == SCAN_BS - 1) bsums[blockIdx.x] = inc;
}

__global__ void __launch_bounds__(SCAN_BS) scan_b_kernel(const int* __restrict__ bsums,
                                                         int* __restrict__ boffs, int nb) {
  __shared__ int wsums[16];
  int v = ((int)threadIdx.x < nb) ? bsums[threadIdx.x] : 0;
  int inc = block_scan_inclusive_1024(v, wsums);
  if ((int)threadIdx.x < nb) boffs[threadIdx.x] = inc - v;
  if ((int)threadIdx.x == nb - 1) boffs[nb] = inc;
}

__global__ void add_offs_kernel(int* __restrict__ v, const int* __restrict__ boffs, int S) {
  int i = blockIdx.x * blockDim.x + threadIdx.x;
  if (i < S) v[i] += boffs[i >> 10];
}

// --- K3: placement. LDS cursors seeded from scanned counts -> absolute pos ---
__global__ void __launch_bounds__(256) bucket_place_kernel(const int* __restrict__ src,
                                                           const int* __restrict__ dst,
                                                           const int* __restrict__ counts,
                                                           int* __restrict__ arr,
                                                           int ne, int B, int NB) {
  __shared__ int cur[NBUCK_MAX];
  for (int k = threadIdx.x; k < B; k += 256) cur[k] = counts[k * NB + blockIdx.x];
  __syncthreads();
  int base = blockIdx.x * EPB;
#pragma unroll 4
  for (int i = 0; i < EPB / 256; ++i) {
    int e = base + i * 256 + threadIdx.x;
    if (e < ne) {
      int d = dst[e];
      int k = d >> BUCKET_BITS;
      int pos = atomicAdd(&cur[k], 1);  // LDS atomic, absolute output slot
      arr[pos] = (src[e] << BUCKET_BITS) | (d & (BUCKET_NODES - 1));
    }
  }
}

// --- K4: one block per bucket; LDS fp32 accumulator + LDS deg; mean + store ---
__global__ void __launch_bounds__(256) bucket_agg_kernel(const float* __restrict__ xin,
                                                         const int* __restrict__ arr,
                                                         const int* __restrict__ counts,
                                                         float* __restrict__ outp,
                                                         int n, int ne, int B, int NB) {
  __shared__ float acc[BUCKET_NODES * 64];
  __shared__ int ldeg[BUCKET_NODES];
  int k0 = blockIdx.x;
  for (int i = threadIdx.x; i < BUCKET_NODES * 64; i += 256) acc[i] = 0.f;
  for (int i = threadIdx.x; i < BUCKET_NODES; i += 256) ldeg[i] = 0;
  __syncthreads();
  int lane = threadIdx.x & 63;
  int wid = __builtin_amdgcn_readfirstlane(threadIdx.x >> 6);
  int start = counts[k0 * NB];
  int end = (k0 + 1 < B) ? counts[(k0 + 1) * NB] : ne;
  int total = end - start;
  int nchunk = total >> 3;  // full 8-edge chunks
  for (int c = wid; c < nchunk; c += 4) {
    int eb = start + c * 8;  // wave-uniform -> scalar loads
    int p0 = arr[eb + 0], p1 = arr[eb + 1], p2 = arr[eb + 2], p3 = arr[eb + 3];
    int p4 = arr[eb + 4], p5 = arr[eb + 5], p6 = arr[eb + 6], p7 = arr[eb + 7];
    float v0 = xin[(size_t)(p0 >> BUCKET_BITS) * 64 + lane];
    float v1 = xin[(size_t)(p1 >> BUCKET_BITS) * 64 + lane];
    float v2 = xin[(size_t)(p2 >> BUCKET_BITS) * 64 + lane];
    float v3 = xin[(size_t)(p3 >> BUCKET_BITS) * 64 + lane];
    float v4 = xin[(size_t)(p4 >> BUCKET_BITS) * 64 + lane];
    float v5 = xin[(size_t)(p5 >> BUCKET_BITS) * 64 + lane];
    float v6 = xin[(size_t)(p6 >> BUCKET_BITS) * 64 + lane];
    float v7 = xin[(size_t)(p7 >> BUCKET_BITS) * 64 + lane];
    atomicAdd(&acc[(p0 & (BUCKET_NODES - 1)) * 64 + lane], v0);
    atomicAdd(&acc[(p1 & (BUCKET_NODES - 1)) * 64 + lane], v1);
    atomicAdd(&acc[(p2 & (BUCKET_NODES - 1)) * 64 + lane], v2);
    atomicAdd(&acc[(p3 & (BUCKET_NODES - 1)) * 64 + lane], v3);
    atomicAdd(&acc[(p4 & (BUCKET_NODES - 1)) * 64 + lane], v4);
    atomicAdd(&acc[(p5 & (BUCKET_NODES - 1)) * 64 + lane], v5);
    atomicAdd(&acc[(p6 & (BUCKET_NODES - 1)) * 64 + lane], v6);
    atomicAdd(&acc[(p7 & (BUCKET_NODES - 1)) * 64 + lane], v7);
    if (lane == 0) {
      atomicAdd(&ldeg[p0 & (BUCKET_NODES - 1)], 1);
      atomicAdd(&ldeg[p1 & (BUCKET_NODES - 1)], 1);
      atomicAdd(&ldeg[p2 & (BUCKET_NODES - 1)], 1);
      atomicAdd(&ldeg[p3 & (BUCKET_NODES - 1)], 1);
      atomicAdd(&ldeg[p4 & (BUCKET_NODES - 1)], 1);
      atomicAdd(&ldeg[p5 & (BUCKET_NODES - 1)], 1);
      atomicAdd(&ldeg[p6 & (BUCKET_NODES - 1)], 1);
      atomicAdd(&ldeg[p7 & (BUCKET_NODES - 1)], 1);
    }
  }
  for (int e = start + nchunk * 8 + wid; e < end; e += 4) {
    int p = arr[e];
    float v = xin[(size_t)(p >> BUCKET_BITS) * 64 + lane];
    atomicAdd(&acc[(p & (BUCKET_NODES - 1)) * 64 + lane], v);
    if (lane == 0) atomicAdd(&ldeg[p & (BUCKET_NODES - 1)], 1);
  }
  __syncthreads();
#pragma unroll 4
  for (int i = 0; i < 32; ++i) {
    int row = wid * 32 + i;
    int node = k0 * BUCKET_NODES + row;
    if (node < n) {
      int d = ldeg[row];
      float inv = 1.0f / (float)((d > 0) ? d : 1);
      outp[(size_t)node * 64 + lane] = acc[row * 64 + lane] * inv;
    }
  }
}

// --- linear layers (unchanged from R4/R5) ---
__global__ void __launch_bounds__(256) lin_relu_kernel(const float* __restrict__ agg,
                                                       const float* __restrict__ xin,
                                                       const float* __restrict__ Wl,
                                                       const float* __restrict__ bias,
                                                       const float* __restrict__ Wr,
                                                       float* __restrict__ outp, int n) {
  int node = blockIdx.x * 256 + threadIdx.x;
  if (node >= n) return;
  const float4* ar = (const float4*)(agg + (size_t)node * 64);
  const float4* xr = (const float4*)(xin + (size_t)node * 64);
#pragma unroll
  for (int h = 0; h < 2; ++h) {
    const float* wl = Wl + h * 32;
    const float* wr = Wr + h * 32;
    float acc[32];
#pragma unroll
    for (int j = 0; j < 32; ++j) acc[j] = bias[h * 32 + j];
#pragma unroll
    for (int k4 = 0; k4 < 16; ++k4) {
      float4 av = ar[k4];
      float4 xv = xr[k4];
#pragma unroll
      for (int j = 0; j < 32; ++j) {
        acc[j] = fmaf(av.x, wl[(k4 * 4 + 0) * 64 + j], acc[j]);
        acc[j] = fmaf(av.y, wl[(k4 * 4 + 1) * 64 + j], acc[j]);
        acc[j] = fmaf(av.z, wl[(k4 * 4 + 2) * 64 + j], acc[j]);
        acc[j] = fmaf(av.w, wl[(k4 * 4 + 3) * 64 + j], acc[j]);
        acc[j] = fmaf(xv.x, wr[(k4 * 4 + 0) * 64 + j], acc[j]);
        acc[j] = fmaf(xv.y, wr[(k4 * 4 + 1) * 64 + j], acc[j]);
        acc[j] = fmaf(xv.z, wr[(k4 * 4 + 2) * 64 + j], acc[j]);
        acc[j] = fmaf(xv.w, wr[(k4 * 4 + 3) * 64 + j], acc[j]);
      }
    }
    float4* op = (float4*)(outp + (size_t)node * 64 + h * 32);
#pragma unroll
    for (int j4 = 0; j4 < 8; ++j4) {
      float4 v;
      v.x = fmaxf(acc[j4 * 4 + 0], 0.f);
      v.y = fmaxf(acc[j4 * 4 + 1], 0.f);
      v.z = fmaxf(acc[j4 * 4 + 2], 0.f);
      v.w = fmaxf(acc[j4 * 4 + 3], 0.f);
      op[j4] = v;
    }
  }
}

__global__ void __launch_bounds__(256) lin2_cls_kernel(const float* __restrict__ agg,
                                                       const float* __restrict__ hin,
                                                       const float* __restrict__ Wl,
                                                       const float* __restrict__ bias,
                                                       const float* __restrict__ Wr,
                                                       const float* __restrict__ Wc,
                                                       const float* __restrict__ bc,
                                                       float* __restrict__ outp, int n) {
  int node = blockIdx.x * 256 + threadIdx.x;
  if (node >= n) return;
  const float4* ar = (const float4*)(agg + (size_t)node * 64);
  const float4* xr = (const float4*)(hin + (size_t)node * 64);
  float p0 = bc[0], p1 = bc[1];
#pragma unroll
  for (int h = 0; h < 2; ++h) {
    const float* wl = Wl + h * 32;
    const float* wr = Wr + h * 32;
    float acc[32];
#pragma unroll
    for (int j = 0; j < 32; ++j) acc[j] = bias[h * 32 + j];
#pragma unroll
    for (int k4 = 0; k4 < 16; ++k4) {
      float4 av = ar[k4];
      float4 xv = xr[k4];
#pragma unroll
      for (int j = 0; j < 32; ++j) {
        acc[j] = fmaf(av.x, wl[(k4 * 4 + 0) * 64 + j], acc[j]);
        acc[j] = fmaf(av.y, wl[(k4 * 4 + 1) * 64 + j], acc[j]);
        acc[j] = fmaf(av.z, wl[(k4 * 4 + 2) * 64 + j], acc[j]);
        acc[j] = fmaf(av.w, wl[(k4 * 4 + 3) * 64 + j], acc[j]);
        acc[j] = fmaf(xv.x, wr[(k4 * 4 + 0) * 64 + j], acc[j]);
        acc[j] = fmaf(xv.y, wr[(k4 * 4 + 1) * 64 + j], acc[j]);
        acc[j] = fmaf(xv.z, wr[(k4 * 4 + 2) * 64 + j], acc[j]);
        acc[j] = fmaf(xv.w, wr[(k4 * 4 + 3) * 64 + j], acc[j]);
      }
    }
#pragma unroll
    for (int j = 0; j < 32; ++j) {
      p0 = fmaf(acc[j], Wc[(h * 32 + j) * 2 + 0], p0);
      p1 = fmaf(acc[j], Wc[(h * 32 + j) * 2 + 1], p1);
    }
  }
  float2 o;
  o.x = p0;
  o.y = p1;
  *(float2*)(outp + (size_t)node * 2) = o;
}

extern "C" void kernel_launch(void* const* d_in, const int* in_sizes, int n_in,
                              void* d_out, int out_size, void* d_ws, size_t ws_size,
                              hipStream_t stream) {
  const float* x   = (const float*)d_in[0];
  const int*   ei  = (const int*)d_in[1];
  const float* W1l = (const float*)d_in[2];
  const float* b1  = (const float*)d_in[3];
  const float* W1r = (const float*)d_in[4];
  const float* W2l = (const float*)d_in[5];
  const float* b2  = (const float*)d_in[6];
  const float* W2r = (const float*)d_in[7];
  const float* Wc  = (const float*)d_in[8];
  const float* bc  = (const float*)d_in[9];
  float* out = (float*)d_out;

  const int n  = in_sizes[0] / 64;   // 100000
  const int ne = in_sizes[1] / 2;    // 1600000
  const int* src = ei;
  const int* dst = ei + ne;

  const int B  = (n + BUCKET_NODES - 1) >> BUCKET_BITS;  // 782 buckets
  const int NB = (ne + EPB - 1) / EPB;                   // 196 blocks
  const int S  = B * NB;                                 // 153272 counts
  const int nsb = (S + SCAN_BS - 1) / SCAN_BS;           // 150 scan blocks (<=1024)

  char* ws = (char*)d_ws;
  size_t off = 0;
  auto carve = [&](size_t bytes) -> void* {
    void* p = ws + off;
    off += (bytes + 255) & ~(size_t)255;
    return p;
  };
  int* counts = (int*)carve((size_t)S * 4);
  int* bsums  = (int*)carve((size_t)(nsb + 1) * 4);
  int* boffs  = (int*)carve((size_t)(nsb + 1) * 4);
  int* arr    = (int*)carve((size_t)ne * 4);
  float* agg  = (float*)carve((size_t)n * 64 * 4);
  float* h    = (float*)carve((size_t)n * 64 * 4);
  (void)ws_size;

  bucket_hist_kernel<<<NB, 256, 0, stream>>>(dst, counts, ne, B, NB);
  scan_a_inplace_kernel<<<nsb, SCAN_BS, 0, stream>>>(counts, bsums, S);
  scan_b_kernel<<<1, SCAN_BS, 0, stream>>>(bsums, boffs, nsb);
  add_offs_kernel<<<(S + 255) / 256, 256, 0, stream>>>(counts, boffs, S);
  bucket_place_kernel<<<NB, 256, 0, stream>>>(src, dst, counts, arr, ne, B, NB);

  bucket_agg_kernel<<<B, 256, 0, stream>>>(x, arr, counts, agg, n, ne, B, NB);
  lin_relu_kernel<<<(n + 255) / 256, 256, 0, stream>>>(agg, x, W1l, b1, W1r, h, n);

  bucket_agg_kernel<<<B, 256, 0, stream>>>(h, arr, counts, agg, n, ne, B, NB);
  lin2_cls_kernel<<<(n + 255) / 256, 256, 0, stream>>>(agg, h, W2l, b2, W2r, Wc, bc, out, n);
}

// Round 3
// 512.771 us; speedup vs baseline: 3.2731x; 3.2731x over previous
//
#include <hip/hip_runtime.h>

// ---------------------------------------------------------------------------
// GraphSAGE 2-layer (mean aggr) + linear classifier, fp32, N=100K, D=64, E=16N
// R7: revert to R4 pipeline (proven 521.9us); R6's bucket-agg regressed 3x
//  (717us/dispatch, VALUBusy 3%, occ 22.6% => latency-bound: 782 blocks of
//  serial gather->LDS-atomic chains vs 100K independent waves).
//  Deltas vs R4:
//   - scatter passes 8 -> 4 (window 1.6MB still L2-resident; halves the
//     redundant 12.8MB/pass edge re-reads; R5 proved 1-pass writeback-bound)
//   - aggregate gather pipeline 8 -> 16 deep (mean deg 16 => one latency
//     round instead of two per wave)
// Linear kernels unchanged (wave-uniform weight s_loads).
// ---------------------------------------------------------------------------

#define SCAN_BS 1024
#define SCATTER_PASSES 4

__global__ void zero_i32_kernel(int* __restrict__ p, int n) {
  int i = blockIdx.x * blockDim.x + threadIdx.x;
  if (i < n) p[i] = 0;
}

__global__ void hist_kernel(const int* __restrict__ dst, int* __restrict__ deg, int ne) {
  int e = blockIdx.x * blockDim.x + threadIdx.x;
  if (e < ne) atomicAdd(&deg[dst[e]], 1);
}

__device__ __forceinline__ int block_scan_inclusive_1024(int v, int* wsums) {
  int lane = threadIdx.x & 63;
  int wid = threadIdx.x >> 6;
  int s = v;
#pragma unroll
  for (int off = 1; off < 64; off <<= 1) {
    int t = __shfl_up(s, off);
    if (lane >= off) s += t;
  }
  if (lane == 63) wsums[wid] = s;
  __syncthreads();
  if (wid == 0) {
    int ws = (lane < 16) ? wsums[lane] : 0;
#pragma unroll
    for (int off = 1; off < 16; off <<= 1) {
      int t = __shfl_up(ws, off);
      if (lane >= off) ws += t;
    }
    if (lane < 16) wsums[lane] = ws;
  }
  __syncthreads();
  if (wid > 0) s += wsums[wid - 1];
  return s;
}

__global__ void __launch_bounds__(SCAN_BS) scan_a_kernel(const int* __restrict__ deg,
                                                         int* __restrict__ local_excl,
                                                         int* __restrict__ bsums, int n) {
  __shared__ int wsums[16];
  int i = blockIdx.x * SCAN_BS + threadIdx.x;
  int v = (i < n) ? deg[i] : 0;
  int inc = block_scan_inclusive_1024(v, wsums);
  if (i < n) local_excl[i] = inc - v;
  if (threadIdx.x == SCAN_BS - 1) bsums[blockIdx.x] = inc;
}

__global__ void __launch_bounds__(SCAN_BS) scan_b_kernel(const int* __restrict__ bsums,
                                                         int* __restrict__ boffs, int nb) {
  __shared__ int wsums[16];
  int v = ((int)threadIdx.x < nb) ? bsums[threadIdx.x] : 0;
  int inc = block_scan_inclusive_1024(v, wsums);
  if ((int)threadIdx.x < nb) boffs[threadIdx.x] = inc - v;
  if ((int)threadIdx.x == nb - 1) boffs[nb] = inc;
}

__global__ void scan_c_kernel(int* __restrict__ row_ptr, int* __restrict__ cursor,
                              const int* __restrict__ boffs, int n, int nb) {
  int i = blockIdx.x * blockDim.x + threadIdx.x;
  if (i < n) {
    int v = row_ptr[i] + boffs[i >> 10];
    row_ptr[i] = v;
    cursor[i] = v;
  }
  if (i == n) row_ptr[n] = boffs[nb];
}

__global__ void scatter_pass_kernel(const int* __restrict__ src, const int* __restrict__ dst,
                                    int* __restrict__ cursor, int* __restrict__ col,
                                    int ne, int lo, int hi) {
  int e = blockIdx.x * blockDim.x + threadIdx.x;
  if (e < ne) {
    int d = dst[e];
    if (d >= lo && d < hi) {
      int pos = atomicAdd(&cursor[d], 1);
      col[pos] = src[e];
    }
  }
}

// one wave per node, one feature per lane; scalarized col reads,
// 16 independent gathers in flight (mean deg = 16 -> ~1 latency round).
__global__ void __launch_bounds__(256) aggregate_kernel(const float* __restrict__ xin,
                                                        const int* __restrict__ row_ptr,
                                                        const int* __restrict__ col,
                                                        float* __restrict__ outp, int n) {
  int gwave = (blockIdx.x * 256 + threadIdx.x) >> 6;
  int lane = threadIdx.x & 63;
  if (gwave >= n) return;
  int m = __builtin_amdgcn_readfirstlane(gwave);
  int start = row_ptr[m];
  int end = row_ptr[m + 1];
  float a[16];
#pragma unroll
  for (int i = 0; i < 16; ++i) a[i] = 0.f;
  int e = start;
  for (; e + 16 <= end; e += 16) {
    int c[16];
#pragma unroll
    for (int i = 0; i < 16; ++i) c[i] = col[e + i];
#pragma unroll
    for (int i = 0; i < 16; ++i) a[i] += xin[(size_t)c[i] * 64 + lane];
  }
  for (; e + 4 <= end; e += 4) {
    int c0 = col[e + 0], c1 = col[e + 1], c2 = col[e + 2], c3 = col[e + 3];
    a[0] += xin[(size_t)c0 * 64 + lane];
    a[1] += xin[(size_t)c1 * 64 + lane];
    a[2] += xin[(size_t)c2 * 64 + lane];
    a[3] += xin[(size_t)c3 * 64 + lane];
  }
  for (; e < end; ++e) a[0] += xin[(size_t)col[e] * 64 + lane];
#pragma unroll
  for (int i = 8; i > 0; i >>= 1)
#pragma unroll
    for (int j = 0; j < i; ++j) a[j] += a[j + i];
  int d = end - start;
  float inv = 1.0f / (float)((d > 0) ? d : 1);
  outp[(size_t)m * 64 + lane] = a[0] * inv;
}

// out = relu(agg @ Wl + b + xin @ Wr); thread-per-node, uniform weight s_loads,
// two j-half passes (acc[32] each) to bound live SGPRs.
__global__ void __launch_bounds__(256) lin_relu_kernel(const float* __restrict__ agg,
                                                       const float* __restrict__ xin,
                                                       const float* __restrict__ Wl,
                                                       const float* __restrict__ bias,
                                                       const float* __restrict__ Wr,
                                                       float* __restrict__ outp, int n) {
  int node = blockIdx.x * 256 + threadIdx.x;
  if (node >= n) return;
  const float4* ar = (const float4*)(agg + (size_t)node * 64);
  const float4* xr = (const float4*)(xin + (size_t)node * 64);
#pragma unroll
  for (int h = 0; h < 2; ++h) {  // uniform half index
    const float* wl = Wl + h * 32;
    const float* wr = Wr + h * 32;
    float acc[32];
#pragma unroll
    for (int j = 0; j < 32; ++j) acc[j] = bias[h * 32 + j];  // uniform -> s_load
#pragma unroll
    for (int k4 = 0; k4 < 16; ++k4) {
      float4 av = ar[k4];
      float4 xv = xr[k4];
#pragma unroll
      for (int j = 0; j < 32; ++j) {
        acc[j] = fmaf(av.x, wl[(k4 * 4 + 0) * 64 + j], acc[j]);
        acc[j] = fmaf(av.y, wl[(k4 * 4 + 1) * 64 + j], acc[j]);
        acc[j] = fmaf(av.z, wl[(k4 * 4 + 2) * 64 + j], acc[j]);
        acc[j] = fmaf(av.w, wl[(k4 * 4 + 3) * 64 + j], acc[j]);
        acc[j] = fmaf(xv.x, wr[(k4 * 4 + 0) * 64 + j], acc[j]);
        acc[j] = fmaf(xv.y, wr[(k4 * 4 + 1) * 64 + j], acc[j]);
        acc[j] = fmaf(xv.z, wr[(k4 * 4 + 2) * 64 + j], acc[j]);
        acc[j] = fmaf(xv.w, wr[(k4 * 4 + 3) * 64 + j], acc[j]);
      }
    }
    float4* op = (float4*)(outp + (size_t)node * 64 + h * 32);
#pragma unroll
    for (int j4 = 0; j4 < 8; ++j4) {
      float4 v;
      v.x = fmaxf(acc[j4 * 4 + 0], 0.f);
      v.y = fmaxf(acc[j4 * 4 + 1], 0.f);
      v.z = fmaxf(acc[j4 * 4 + 2], 0.f);
      v.w = fmaxf(acc[j4 * 4 + 3], 0.f);
      op[j4] = v;
    }
  }
}

// h2 = agg @ Wl + b + hin @ Wr; out = h2 @ Wc + bc  -> [n, 2]
// thread-per-node; classifier folded into each half-pass epilogue (uniform Wc).
__global__ void __launch_bounds__(256) lin2_cls_kernel(const float* __restrict__ agg,
                                                       const float* __restrict__ hin,
                                                       const float* __restrict__ Wl,
                                                       const float* __restrict__ bias,
                                                       const float* __restrict__ Wr,
                                                       const float* __restrict__ Wc,
                                                       const float* __restrict__ bc,
                                                       float* __restrict__ outp, int n) {
  int node = blockIdx.x * 256 + threadIdx.x;
  if (node >= n) return;
  const float4* ar = (const float4*)(agg + (size_t)node * 64);
  const float4* xr = (const float4*)(hin + (size_t)node * 64);
  float p0 = bc[0], p1 = bc[1];  // uniform s_loads
#pragma unroll
  for (int h = 0; h < 2; ++h) {
    const float* wl = Wl + h * 32;
    const float* wr = Wr + h * 32;
    float acc[32];
#pragma unroll
    for (int j = 0; j < 32; ++j) acc[j] = bias[h * 32 + j];
#pragma unroll
    for (int k4 = 0; k4 < 16; ++k4) {
      float4 av = ar[k4];
      float4 xv = xr[k4];
#pragma unroll
      for (int j = 0; j < 32; ++j) {
        acc[j] = fmaf(av.x, wl[(k4 * 4 + 0) * 64 + j], acc[j]);
        acc[j] = fmaf(av.y, wl[(k4 * 4 + 1) * 64 + j], acc[j]);
        acc[j] = fmaf(av.z, wl[(k4 * 4 + 2) * 64 + j], acc[j]);
        acc[j] = fmaf(av.w, wl[(k4 * 4 + 3) * 64 + j], acc[j]);
        acc[j] = fmaf(xv.x, wr[(k4 * 4 + 0) * 64 + j], acc[j]);
        acc[j] = fmaf(xv.y, wr[(k4 * 4 + 1) * 64 + j], acc[j]);
        acc[j] = fmaf(xv.z, wr[(k4 * 4 + 2) * 64 + j], acc[j]);
        acc[j] = fmaf(xv.w, wr[(k4 * 4 + 3) * 64 + j], acc[j]);
      }
    }
#pragma unroll
    for (int j = 0; j < 32; ++j) {
      p0 = fmaf(acc[j], Wc[(h * 32 + j) * 2 + 0], p0);  // uniform -> s_load
      p1 = fmaf(acc[j], Wc[(h * 32 + j) * 2 + 1], p1);
    }
  }
  float2 o;
  o.x = p0;
  o.y = p1;
  *(float2*)(outp + (size_t)node * 2) = o;
}

extern "C" void kernel_launch(void* const* d_in, const int* in_sizes, int n_in,
                              void* d_out, int out_size, void* d_ws, size_t ws_size,
                              hipStream_t stream) {
  const float* x   = (const float*)d_in[0];
  const int*   ei  = (const int*)d_in[1];
  const float* W1l = (const float*)d_in[2];
  const float* b1  = (const float*)d_in[3];
  const float* W1r = (const float*)d_in[4];
  const float* W2l = (const float*)d_in[5];
  const float* b2  = (const float*)d_in[6];
  const float* W2r = (const float*)d_in[7];
  const float* Wc  = (const float*)d_in[8];
  const float* bc  = (const float*)d_in[9];
  float* out = (float*)d_out;

  const int n  = in_sizes[0] / 64;   // 100000
  const int ne = in_sizes[1] / 2;    // 1600000
  const int* src = ei;
  const int* dst = ei + ne;

  char* ws = (char*)d_ws;
  size_t off = 0;
  auto carve = [&](size_t bytes) -> void* {
    void* p = ws + off;
    off += (bytes + 255) & ~(size_t)255;
    return p;
  };
  const int nb = (n + SCAN_BS - 1) / SCAN_BS;  // 98
  int* deg     = (int*)carve((size_t)n * 4);
  int* row_ptr = (int*)carve((size_t)(n + 1) * 4);
  int* cursor  = (int*)carve((size_t)n * 4);
  int* bsums   = (int*)carve((size_t)(nb + 1) * 4);
  int* boffs   = (int*)carve((size_t)(nb + 1) * 4);
  int* col     = (int*)carve((size_t)ne * 4);
  float* agg   = (float*)carve((size_t)n * 64 * 4);
  float* h     = (float*)carve((size_t)n * 64 * 4);
  (void)ws_size;

  zero_i32_kernel<<<(n + 255) / 256, 256, 0, stream>>>(deg, n);
  hist_kernel<<<(ne + 255) / 256, 256, 0, stream>>>(dst, deg, ne);

  scan_a_kernel<<<nb, SCAN_BS, 0, stream>>>(deg, row_ptr, bsums, n);
  scan_b_kernel<<<1, SCAN_BS, 0, stream>>>(bsums, boffs, nb);
  scan_c_kernel<<<(n + 256) / 256, 256, 0, stream>>>(row_ptr, cursor, boffs, n, nb);

  {
    int W = (n + SCATTER_PASSES - 1) / SCATTER_PASSES;
    for (int p = 0; p < SCATTER_PASSES; ++p) {
      int lo = p * W;
      int hi = (lo + W < n) ? (lo + W) : n;
      scatter_pass_kernel<<<(ne + 255) / 256, 256, 0, stream>>>(src, dst, cursor, col, ne, lo, hi);
    }
  }

  aggregate_kernel<<<(n * 64 + 255) / 256, 256, 0, stream>>>(x, row_ptr, col, agg, n);
  lin_relu_kernel<<<(n + 255) / 256, 256, 0, stream>>>(agg, x, W1l, b1, W1r, h, n);

  aggregate_kernel<<<(n * 64 + 255) / 256, 256, 0, stream>>>(h, row_ptr, col, agg, n);
  lin2_cls_kernel<<<(n + 255) / 256, 256, 0, stream>>>(agg, h, W2l, b2, W2r, Wc, bc, out, n);
}